// Round 13
// baseline (741.173 us; speedup 1.0000x reference)
//
#include <hip/hip_runtime.h>
#include <math.h>

#define BATCH 2048
#define SEQ   128
#define HID   512
#define OUTT  24
#define RPB   32              // batch rows per block = two 16-row MFMA subtiles
#define NBLK  (BATCH/RPB)     // 64 blocks: stream amortized over 2x MFMA work
#define TPB   1024            // 16 waves = 4/SIMD
#define NTW   2               // n-tiles per wave (16 waves x 2 = 32 n-tiles = 512 cols)
#define KTN   (HID/32)        // 16 k-tiles
#define LDSB_KT 2             // k-tiles resident in LDS (64 KB)
#define STR_KT  (KTN - LDSB_KT)             // 14 streamed from L2 per step
#define LDSB_BASE 0                         // kt 0..1 in LDS
#define STR_BASE  LDSB_KT                   // kt 2..15 streamed
#define ATILE 8192            // halves in one 16-row A subtile
#define PFD   3               // rolling prefetch lookahead (4 MFMAs/tile -> ~230cy cover)
#define PRIME 2               // tiles primed during PREVIOUS step's epilogue

typedef _Float16 half8 __attribute__((ext_vector_type(8)));
typedef float   floatx4 __attribute__((ext_vector_type(4)));

__device__ __forceinline__ void mfma_hv(floatx4& c, half8 a, half8 b) {
    c = __builtin_amdgcn_mfma_f32_16x16x32_f16(a, b, c, 0, 0, 0);
}

// fast tanh: 1 - 2/(e^{2x}+1), e^{2x} = 2^(x*2/ln2). Saturates correctly.
__device__ __forceinline__ float ftanh(float x) {
    float e = __builtin_amdgcn_exp2f(x * 2.885390081777927f);
    float r = __builtin_amdgcn_rcpf(e + 1.0f);
    return fmaf(-2.0f, r, 1.0f);
}

// Pack W[j][k] (row-major HIDxHID fp32) into per-lane MFMA B-fragment layout,
// fp16: frag[(kt*32+nt)*64 + lane][8]; lane holds
// B[k = kt*32 + (lane>>4)*8 + jj][n = nt*16 + (lane&15)] = W[n][k].
__global__ __launch_bounds__(256) void pack_wfrag(const float* __restrict__ W,
                                                  _Float16* __restrict__ Bw)
{
    int id   = blockIdx.x * 256 + threadIdx.x;
    int lane = id & 63;
    int nt   = (id >> 6) & 31;
    int kt   = id >> 11;
    int n  = nt * 16 + (lane & 15);
    int k0 = kt * 32 + (lane >> 4) * 8;
    const float* src = W + (size_t)n * HID + k0;
    half8 v;
    #pragma unroll
    for (int j = 0; j < 8; j++) v[j] = (_Float16)src[j];
    *(half8*)&Bw[(size_t)id * 8] = v;
}

// Swizzled A layout per 16-row subtile: el(m,k) = (k>>5)*512 + G*128 +
// ((m^G)<<3) + (k&7), G=(k>>3)&3. Subtile 0 = batch rows 0-15, subtile 1 =
// rows 16-31. Double-buffered: MFMA reads A[cur][*], epilogue writes A[nxt][*].
// Reader lane (q,c), k-tile kt: contiguous aligned 16 B at kt*512 + q*128 + ((c^q)<<3).
__global__ __launch_bounds__(TPB)
__attribute__((amdgpu_waves_per_eu(4, 4)))
void rnn_persist(
    const float* __restrict__ x,
    const _Float16* __restrict__ BwE,
    const _Float16* __restrict__ BwD,
    const float* __restrict__ encWih, const float* __restrict__ encBih,
    const float* __restrict__ encBhh,
    const float* __restrict__ decWih, const float* __restrict__ decBih,
    const float* __restrict__ decBhh,
    const float* __restrict__ fcW, const float* __restrict__ fcB,
    float* __restrict__ out)
{
    __shared__ _Float16 A[2][2][ATILE];         // 64 KB: [buf][subtile][16x512]
    __shared__ _Float16 BwL[LDSB_KT * 16384];   // 64 KB LDS-resident weight k-tiles
    __shared__ float    xs[RPB][SEQ];           // 16 KB
    __shared__ float    dec_in_s[RPB];

    const int tid  = threadIdx.x;
    const int lane = tid & 63;
    const int wv   = tid >> 6;                  // 0..15
    const int row0 = blockIdx.x * RPB;
    const int c    = lane & 15;
    const int q    = lane >> 4;
    const int mB   = q * 4;                     // subtile D rows owned: mB..mB+3

    const float fcb0 = fcB[0];

    // ---- t-invariant epilogue state in registers ----
    int   moff[NTW][4];           // A write offsets within a subtile (t-invariant)
    float wiR[NTW], bbR[NTW];     // swapped enc->dec once at t==SEQ
    #pragma unroll
    for (int i = 0; i < NTW; i++) {
        int n = (wv * NTW + i) * 16 + c;
        int G = (n >> 3) & 3;
        int base = (n >> 5) * 512 + G * 128 + (n & 7);
        #pragma unroll
        for (int r = 0; r < 4; r++)
            moff[i][r] = base + (((mB + r) ^ G) << 3);
        wiR[i] = encWih[n];
        bbR[i] = encBih[n] + encBhh[n];
    }

    // preload x block-slice into LDS (coalesced float4): 32 rows x 128
    {
        const float4* xg = (const float4*)(x + (size_t)row0 * SEQ);
        if (tid < RPB * SEQ / 4) ((float4*)xs)[tid] = xg[tid];
    }

    // h0 = 0 (both subtiles of buf 0)
    for (int i = tid; i < 2 * ATILE / 2; i += TPB) ((int*)A[0])[i] = 0;

    // stage encoder LDS-resident weight k-tiles (64 KB)
    {
        const float4* src = (const float4*)(BwE + (size_t)LDSB_BASE * 16384);
        float4* dst = (float4*)BwL;
        #pragma unroll
        for (int i = 0; i < LDSB_KT * 16384 / 8 / TPB; i++)
            dst[i * TPB + tid] = src[i * TPB + tid];
    }

    const int    ldsAoff = q * 128 + ((c ^ q) << 3);
    const size_t bbase   = (size_t)(wv * NTW) * 512 + (size_t)lane * 8;
    const int    bbL     = wv * NTW * 512 + lane * 8;

    // streamed-B register window; fully-unrolled indexing only
    half8 sb[STR_KT][NTW];
    #pragma unroll
    for (int p = 0; p < PRIME; p++)
        #pragma unroll
        for (int i = 0; i < NTW; i++)
            sb[p][i] = *(const half8*)&BwE[bbase + (size_t)(STR_BASE + p) * 16384 + i * 512];

    __syncthreads();

    int cur = 0;
    for (int t = 0; t < SEQ + OUTT; t++) {
        const bool enc = (t < SEQ);
        const _Float16* __restrict__ Bw = enc ? BwE : BwD;

        if (t == SEQ) {   // one-time swap to decoder weights (LDS tiles + consts)
            #pragma unroll
            for (int i = 0; i < NTW; i++) {
                int n = (wv * NTW + i) * 16 + c;
                wiR[i] = decWih[n];
                bbR[i] = decBih[n] + decBhh[n];
            }
            const float4* src = (const float4*)(BwD + (size_t)LDSB_BASE * 16384);
            float4* dst = (float4*)BwL;
            #pragma unroll
            for (int i = 0; i < LDSB_KT * 16384 / 8 / TPB; i++)
                dst[i * TPB + tid] = src[i * TPB + tid];
            __syncthreads();
        }

        floatx4 acc0[NTW], acc1[NTW];
        #pragma unroll
        for (int i = 0; i < NTW; i++) {
            acc0[i] = (floatx4){0.f, 0.f, 0.f, 0.f};
            acc1[i] = (floatx4){0.f, 0.f, 0.f, 0.f};
        }

        __builtin_amdgcn_s_setprio(1);

        // extend lookahead PRIME -> PFD at phase start
        #pragma unroll
        for (int p = PRIME; p < PFD; p++)
            #pragma unroll
            for (int i = 0; i < NTW; i++)
                sb[p][i] = *(const half8*)&Bw[bbase + (size_t)(STR_BASE + p) * 16384 + i * 512];

        // LDS-resident k-tiles: both subtiles share each B fragment
        #pragma unroll
        for (int kl = 0; kl < LDSB_KT; kl++) {
            half8 a0 = *(const half8*)&A[cur][0][(LDSB_BASE + kl) * 512 + ldsAoff];
            half8 a1 = *(const half8*)&A[cur][1][(LDSB_BASE + kl) * 512 + ldsAoff];
            #pragma unroll
            for (int i = 0; i < NTW; i++) {
                half8 b = *(const half8*)&BwL[kl * 16384 + bbL + i * 512];
                mfma_hv(acc0[i], a0, b);
                mfma_hv(acc1[i], a1, b);
            }
        }

        // streamed k-tiles with rolling prefetch (4 MFMAs per tile)
        #pragma unroll
        for (int s = 0; s < STR_KT; s++) {
            const int kt = STR_BASE + s;
            if (s + PFD < STR_KT) {
                #pragma unroll
                for (int i = 0; i < NTW; i++)
                    sb[s + PFD][i] = *(const half8*)&Bw[bbase + (size_t)(kt + PFD) * 16384 + i * 512];
            }
            half8 a0 = *(const half8*)&A[cur][0][kt * 512 + ldsAoff];
            half8 a1 = *(const half8*)&A[cur][1][kt * 512 + ldsAoff];
            #pragma unroll
            for (int i = 0; i < NTW; i++) {
                mfma_hv(acc0[i], a0, sb[s][i]);
                mfma_hv(acc1[i], a1, sb[s][i]);
            }
        }

        __builtin_amdgcn_s_setprio(0);

        // ---- epilogue (no barrier before: writes go to A[nxt]) ----
        const int nxt = cur ^ 1;

        // prime next step's first PRIME streamed tiles; L2 latency hides under tanh
        {
            const _Float16* __restrict__ Bwn = (t + 1 < SEQ) ? BwE : BwD;
            #pragma unroll
            for (int p = 0; p < PRIME; p++)
                #pragma unroll
                for (int i = 0; i < NTW; i++)
                    sb[p][i] = *(const half8*)&Bwn[bbase + (size_t)(STR_BASE + p) * 16384 + i * 512];
        }

        float inp0[4], inp1[4];
        if (enc) {
            #pragma unroll
            for (int r = 0; r < 4; r++) { inp0[r] = xs[mB + r][t]; inp1[r] = xs[16 + mB + r][t]; }
        } else if (t == SEQ) {
            #pragma unroll
            for (int r = 0; r < 4; r++) { inp0[r] = xs[mB + r][SEQ - 1]; inp1[r] = xs[16 + mB + r][SEQ - 1]; }
        } else {
            #pragma unroll
            for (int r = 0; r < 4; r++) { inp0[r] = dec_in_s[mB + r]; inp1[r] = dec_in_s[16 + mB + r]; }
        }

        #pragma unroll
        for (int i = 0; i < NTW; i++) {
            #pragma unroll
            for (int r = 0; r < 4; r++) {
                float v0 = ftanh(acc0[i][r] + inp0[r] * wiR[i] + bbR[i]);
                float v1 = ftanh(acc1[i][r] + inp1[r] * wiR[i] + bbR[i]);
                A[nxt][0][moff[i][r]] = (_Float16)v0;
                A[nxt][1][moff[i][r]] = (_Float16)v1;
            }
        }
        __syncthreads();   // A[nxt] complete (single barrier per encode step)

        if (!enc) {
            // FC: wave wv reduces batch rows wv (subtile0) and wv+16 (subtile1)
            const _Float16* An0 = A[nxt][0];
            const _Float16* An1 = A[nxt][1];
            float s0 = 0.f, s1 = 0.f;
            #pragma unroll
            for (int ii = 0; ii < HID / 64; ii++) {
                int k = ii * 64 + lane;
                int G = (k >> 3) & 3;
                int a0 = (k >> 5) * 512 + G * 128 + (k & 7) + ((wv ^ G) << 3);
                float w = fcW[k];
                s0 = fmaf((float)An0[a0], w, s0);
                s1 = fmaf((float)An1[a0], w, s1);
            }
            #pragma unroll
            for (int off = 32; off > 0; off >>= 1) {
                s0 += __shfl_down(s0, off, 64);
                s1 += __shfl_down(s1, off, 64);
            }
            if (lane == 0) {
                float o0 = s0 + fcb0, o1 = s1 + fcb0;
                dec_in_s[wv]      = o0;
                dec_in_s[wv + 16] = o1;
                out[(size_t)(row0 + wv) * OUTT + (t - SEQ)]      = o0;
                out[(size_t)(row0 + 16 + wv) * OUTT + (t - SEQ)] = o1;
            }
            __syncthreads();   // dec_in_s ready for next step's epilogue
        }
        cur = nxt;
    }
}

extern "C" void kernel_launch(void* const* d_in, const int* in_sizes, int n_in,
                              void* d_out, int out_size, void* d_ws, size_t ws_size,
                              hipStream_t stream)
{
    const float* x        = (const float*)d_in[0];
    const float* enc_Wih  = (const float*)d_in[1];
    const float* enc_Whh  = (const float*)d_in[2];
    const float* enc_bih  = (const float*)d_in[3];
    const float* enc_bhh  = (const float*)d_in[4];
    const float* dec_Wih  = (const float*)d_in[5];
    const float* dec_Whh  = (const float*)d_in[6];
    const float* dec_bih  = (const float*)d_in[7];
    const float* dec_bhh  = (const float*)d_in[8];
    const float* fc_W     = (const float*)d_in[9];
    const float* fc_b     = (const float*)d_in[10];
    float* out = (float*)d_out;

    const size_t wfrag = (size_t)HID * HID;
    _Float16* BwE = (_Float16*)d_ws;
    _Float16* BwD = BwE + wfrag;

    pack_wfrag<<<HID * HID / (256 * 8), 256, 0, stream>>>(enc_Whh, BwE);
    pack_wfrag<<<HID * HID / (256 * 8), 256, 0, stream>>>(dec_Whh, BwD);

    rnn_persist<<<NBLK, TPB, 0, stream>>>(
        x, BwE, BwD,
        enc_Wih, enc_bih, enc_bhh,
        dec_Wih, dec_bih, dec_bhh,
        fc_W, fc_b, out);
}

// Round 15
// 612.234 us; speedup vs baseline: 1.2106x; 1.2106x over previous
//
#include <hip/hip_runtime.h>
#include <math.h>

#define BATCH 2048
#define SEQ   128
#define HID   512
#define OUTT  24
#define RPB   16              // batch rows per block = one M=16 MFMA tile (fp16 state)
#define NBLK  (BATCH/RPB)     // 128 blocks
#define TPB   1024            // 16 waves = 4/SIMD
#define NTW   2               // n-tiles per wave (16 waves x 2 = 32 n-tiles = 512 cols)
#define KTN   (HID/32)        // 16 k-tiles
#define LDSB_KT 3             // k-tiles resident in LDS (96 KB; A dbuf takes 32 KB)
#define STR_KT  (KTN - LDSB_KT)             // 13 streamed from L2 per step
#define LDSB_BASE 0                         // kt 0..2 in LDS
#define STR_BASE  LDSB_KT                   // kt 3..15 streamed
#define ATILE 8192            // halves in one A tile (16 rows x 512 k)
#define PFD   4               // rolling prefetch lookahead inside MFMA phase
#define PRIME 3               // tiles primed during PREVIOUS step's epilogue

typedef _Float16 half8 __attribute__((ext_vector_type(8)));
typedef float   floatx4 __attribute__((ext_vector_type(4)));

__device__ __forceinline__ void mfma_hv(floatx4& c, half8 a, half8 b) {
    c = __builtin_amdgcn_mfma_f32_16x16x32_f16(a, b, c, 0, 0, 0);
}

// fast tanh: 1 - 2/(e^{2x}+1), e^{2x} = 2^(x*2/ln2). Saturates correctly.
__device__ __forceinline__ float ftanh(float x) {
    float e = __builtin_amdgcn_exp2f(x * 2.885390081777927f);
    float r = __builtin_amdgcn_rcpf(e + 1.0f);
    return fmaf(-2.0f, r, 1.0f);
}

// Pack W[j][k] (row-major HIDxHID fp32) into per-lane MFMA B-fragment layout,
// fp16: frag[(kt*32+nt)*64 + lane][8]; lane holds
// B[k = kt*32 + (lane>>4)*8 + jj][n = nt*16 + (lane&15)] = W[n][k].
__global__ __launch_bounds__(256) void pack_wfrag(const float* __restrict__ W,
                                                  _Float16* __restrict__ Bw)
{
    int id   = blockIdx.x * 256 + threadIdx.x;
    int lane = id & 63;
    int nt   = (id >> 6) & 31;
    int kt   = id >> 11;
    int n  = nt * 16 + (lane & 15);
    int k0 = kt * 32 + (lane >> 4) * 8;
    const float* src = W + (size_t)n * HID + k0;
    half8 v;
    #pragma unroll
    for (int j = 0; j < 8; j++) v[j] = (_Float16)src[j];
    *(half8*)&Bw[(size_t)id * 8] = v;
}

// Swizzled A layout: el(m,k) = (k>>5)*512 + G*128 + ((m^G)<<3) + (k&7), G=(k>>3)&3.
// Double-buffered fp16 state: MFMA reads A[cur], epilogue writes A[cur^1] ->
// no mid-step barrier. Decode FC runs with NO trailing barrier: its only
// consumer (dec_in_s read) is fenced by a barrier at the NEXT step's epilogue.
__global__ __launch_bounds__(TPB)
__attribute__((amdgpu_waves_per_eu(4, 4)))
void rnn_persist(
    const float* __restrict__ x,
    const _Float16* __restrict__ BwE,
    const _Float16* __restrict__ BwD,
    const float* __restrict__ encWih, const float* __restrict__ encBih,
    const float* __restrict__ encBhh,
    const float* __restrict__ decWih, const float* __restrict__ decBih,
    const float* __restrict__ decBhh,
    const float* __restrict__ fcW, const float* __restrict__ fcB,
    float* __restrict__ out)
{
    __shared__ _Float16 A[2][ATILE];            // 32 KB double-buffered h state
    __shared__ _Float16 BwL[LDSB_KT * 16384];   // 96 KB LDS-resident weight k-tiles
    __shared__ float    xs[RPB][SEQ];           // 8 KB
    __shared__ float    dec_in_s[RPB];

    const int tid  = threadIdx.x;
    const int lane = tid & 63;
    const int wv   = tid >> 6;                  // 0..15
    const int row0 = blockIdx.x * RPB;
    const int c    = lane & 15;
    const int q    = lane >> 4;
    const int mB   = q * 4;                     // D rows owned: mB..mB+3 (0..15)

    const float fcb0 = fcB[0];

    // ---- t-invariant epilogue state, all in registers ----
    int   nIdx[NTW];
    int   moff[NTW][4];           // A write offsets (t-invariant)
    float wiR[NTW], bbR[NTW];     // swapped enc->dec once at t==SEQ
    #pragma unroll
    for (int i = 0; i < NTW; i++) {
        int n = (wv * NTW + i) * 16 + c;
        nIdx[i] = n;
        int G = (n >> 3) & 3;
        int base = (n >> 5) * 512 + G * 128 + (n & 7);
        #pragma unroll
        for (int r = 0; r < 4; r++)
            moff[i][r] = base + (((mB + r) ^ G) << 3);
        wiR[i] = encWih[n];
        bbR[i] = encBih[n] + encBhh[n];
    }
    // FC constants (wave wv reduces batch row wv)
    int   aFC[HID / 64];
    float fcw[HID / 64];
    #pragma unroll
    for (int ii = 0; ii < HID / 64; ii++) {
        int k = ii * 64 + lane;
        int G = (k >> 3) & 3;
        aFC[ii] = (k >> 5) * 512 + G * 128 + (k & 7) + ((wv ^ G) << 3);
        fcw[ii] = fcW[k];
    }

    // preload x block-slice into LDS (coalesced float4): 16 rows x 128
    {
        const float4* xg = (const float4*)(x + (size_t)row0 * SEQ);
        if (tid < RPB * SEQ / 4) ((float4*)xs)[tid] = xg[tid];
    }

    // h0 = 0
    for (int i = tid; i < ATILE / 2; i += TPB) ((int*)A[0])[i] = 0;

    // stage encoder LDS-resident weight k-tiles (96 KB)
    {
        const float4* src = (const float4*)(BwE + (size_t)LDSB_BASE * 16384);
        float4* dst = (float4*)BwL;
        #pragma unroll
        for (int i = 0; i < LDSB_KT * 16384 / 8 / TPB; i++)
            dst[i * TPB + tid] = src[i * TPB + tid];
    }

    const int    ldsAoff = q * 128 + ((c ^ q) << 3);
    const size_t bbase   = (size_t)(wv * NTW) * 512 + (size_t)lane * 8;
    const int    bbL     = wv * NTW * 512 + lane * 8;

    // streamed-B register file; entries written in fully-unrolled loops only
    half8 sb[STR_KT][NTW];
    // prime first PRIME tiles for t=0
    #pragma unroll
    for (int p = 0; p < PRIME; p++)
        #pragma unroll
        for (int i = 0; i < NTW; i++)
            sb[p][i] = *(const half8*)&BwE[bbase + (size_t)(STR_BASE + p) * 16384 + i * 512];

    __syncthreads();

    int cur = 0;
    for (int t = 0; t < SEQ + OUTT; t++) {
        const bool enc = (t < SEQ);
        const _Float16* __restrict__ Bw = enc ? BwE : BwD;

        if (t == SEQ) {   // one-time swap to decoder weights (LDS tiles + consts)
            #pragma unroll
            for (int i = 0; i < NTW; i++) {
                wiR[i] = decWih[nIdx[i]];
                bbR[i] = decBih[nIdx[i]] + decBhh[nIdx[i]];
            }
            const float4* src = (const float4*)(BwD + (size_t)LDSB_BASE * 16384);
            float4* dst = (float4*)BwL;
            #pragma unroll
            for (int i = 0; i < LDSB_KT * 16384 / 8 / TPB; i++)
                dst[i * TPB + tid] = src[i * TPB + tid];
            __syncthreads();
        }

        floatx4 acc[NTW];
        #pragma unroll
        for (int i = 0; i < NTW; i++) acc[i] = (floatx4){0.f, 0.f, 0.f, 0.f};

        __builtin_amdgcn_s_setprio(1);

        // extend lookahead PRIME -> PFD at phase start
        #pragma unroll
        for (int p = PRIME; p < PFD; p++)
            #pragma unroll
            for (int i = 0; i < NTW; i++)
                sb[p][i] = *(const half8*)&Bw[bbase + (size_t)(STR_BASE + p) * 16384 + i * 512];

        // LDS-resident k-tiles (reads A[cur])
        #pragma unroll
        for (int kl = 0; kl < LDSB_KT; kl++) {
            half8 a = *(const half8*)&A[cur][(LDSB_BASE + kl) * 512 + ldsAoff];
            #pragma unroll
            for (int i = 0; i < NTW; i++) {
                half8 b = *(const half8*)&BwL[kl * 16384 + bbL + i * 512];
                mfma_hv(acc[i], a, b);
            }
        }

        // streamed k-tiles with rolling prefetch
        #pragma unroll
        for (int s = 0; s < STR_KT; s++) {
            const int kt = STR_BASE + s;
            if (s + PFD < STR_KT) {
                #pragma unroll
                for (int i = 0; i < NTW; i++)
                    sb[s + PFD][i] = *(const half8*)&Bw[bbase + (size_t)(kt + PFD) * 16384 + i * 512];
            }
            half8 a = *(const half8*)&A[cur][kt * 512 + ldsAoff];
            #pragma unroll
            for (int i = 0; i < NTW; i++)
                mfma_hv(acc[i], a, sb[s][i]);
        }

        __builtin_amdgcn_s_setprio(0);

        // ---- epilogue (no barrier before: writes go to A[nxt]) ----
        const int nxt = cur ^ 1;

        // prime next step's first PRIME streamed tiles NOW -> L2 latency+delivery
        // hides under the tanh VALU below.
        {
            const _Float16* __restrict__ Bwn = (t + 1 < SEQ) ? BwE : BwD;
            #pragma unroll
            for (int p = 0; p < PRIME; p++)
                #pragma unroll
                for (int i = 0; i < NTW; i++)
                    sb[p][i] = *(const half8*)&Bwn[bbase + (size_t)(STR_BASE + p) * 16384 + i * 512];
        }

        // fence for dec_in_s: previous step's FC (no trailing barrier) must be
        // visible before we read it. Uniform condition -> legal barrier.
        if (t > SEQ) __syncthreads();

        float inp[4];
        if (enc) {
            #pragma unroll
            for (int r = 0; r < 4; r++) inp[r] = xs[mB + r][t];
        } else if (t == SEQ) {
            #pragma unroll
            for (int r = 0; r < 4; r++) inp[r] = xs[mB + r][SEQ - 1];
        } else {
            #pragma unroll
            for (int r = 0; r < 4; r++) inp[r] = dec_in_s[mB + r];
        }

        #pragma unroll
        for (int i = 0; i < NTW; i++) {
            #pragma unroll
            for (int r = 0; r < 4; r++) {
                float v = ftanh(acc[i][r] + inp[r] * wiR[i] + bbR[i]);
                A[nxt][moff[i][r]] = (_Float16)v;
            }
        }
        __syncthreads();   // A[nxt] complete (single barrier per encode step)

        if (!enc) {
            // FC: wave wv reduces batch row wv; NO trailing barrier -- runs
            // concurrently with next step's MFMA phase (reads A[nxt], which
            // next step only reads; next epilogue writes the other buffer).
            const _Float16* An = A[nxt];
            float sfc = 0.f;
            #pragma unroll
            for (int ii = 0; ii < HID / 64; ii++)
                sfc = fmaf((float)An[aFC[ii]], fcw[ii], sfc);
            #pragma unroll
            for (int off = 32; off > 0; off >>= 1)
                sfc += __shfl_down(sfc, off, 64);
            if (lane == 0) {
                float o = sfc + fcb0;
                dec_in_s[wv] = o;
                out[(size_t)(row0 + wv) * OUTT + (t - SEQ)] = o;
            }
        }
        cur = nxt;
    }
}

extern "C" void kernel_launch(void* const* d_in, const int* in_sizes, int n_in,
                              void* d_out, int out_size, void* d_ws, size_t ws_size,
                              hipStream_t stream)
{
    const float* x        = (const float*)d_in[0];
    const float* enc_Wih  = (const float*)d_in[1];
    const float* enc_Whh  = (const float*)d_in[2];
    const float* enc_bih  = (const float*)d_in[3];
    const float* enc_bhh  = (const float*)d_in[4];
    const float* dec_Wih  = (const float*)d_in[5];
    const float* dec_Whh  = (const float*)d_in[6];
    const float* dec_bih  = (const float*)d_in[7];
    const float* dec_bhh  = (const float*)d_in[8];
    const float* fc_W     = (const float*)d_in[9];
    const float* fc_b     = (const float*)d_in[10];
    float* out = (float*)d_out;

    const size_t wfrag = (size_t)HID * HID;
    _Float16* BwE = (_Float16*)d_ws;
    _Float16* BwD = BwE + wfrag;

    pack_wfrag<<<HID * HID / (256 * 8), 256, 0, stream>>>(enc_Whh, BwE);
    pack_wfrag<<<HID * HID / (256 * 8), 256, 0, stream>>>(dec_Whh, BwD);

    rnn_persist<<<NBLK, TPB, 0, stream>>>(
        x, BwE, BwD,
        enc_Wih, enc_bih, enc_bhh,
        dec_Wih, dec_bih, dec_bhh,
        fc_W, fc_b, out);
}